// Round 19
// baseline (210.847 us; speedup 1.0000x reference)
//
#include <hip/hip_runtime.h>
#include <math.h>

#define NB 8
#define NN 4096   // pixels per batch
#define NC 128    // channels

typedef __attribute__((ext_vector_type(8)))  short bf16x8;
typedef __attribute__((ext_vector_type(4)))  float f32x4;
typedef __attribute__((ext_vector_type(16))) float f32x16;

#define L2E   1.4426950408889634f
#define SBIAS 43.2808512266689f   /* 30 * log2(e) */

static __device__ __forceinline__ float fexp2(float x) { return __builtin_amdgcn_exp2f(x); }
static __device__ __forceinline__ float flog2(float x) { return __builtin_amdgcn_logf(x); }

static __device__ __forceinline__ unsigned short f2bf(float f) {
    unsigned u = __builtin_bit_cast(unsigned, f);
    return (unsigned short)((u + 0x7FFFu + ((u >> 16) & 1u)) >> 16);
}

// ---------------------------------------------------------------------------
// PACKED LAYOUTS (bf16 element offsets):
//  fx/gx: tile T = (b*128 + n>>5), kc = k>>4:
//    fpk[((T*8 + kc)*64 + lane)*8 + j] = x[b][n = 32*(T&127) + (lane&31)]
//                                         [k = kc*16 + (lane>>5)*8 + j]
//  ht: hpk[((((b*4+cb)*128 + nc)*2 + s)*64 + lane)*8 + j]
//       = h[b][c = cb*32 + (lane&31)][n = nc*32 + s*16 + (lane>>5)*8 + j]
// Fragment loads become base + lane*16 : perfectly coalesced.
// ---------------------------------------------------------------------------

// ---------------------------------------------------------------------------
// K1: projections f,g,h (fp32 compute, bf16 PACKED outputs).
// ---------------------------------------------------------------------------
__global__ __launch_bounds__(256) void k_proj(
    const float* __restrict__ x,
    const float* __restrict__ Wf, const float* __restrict__ bf,
    const float* __restrict__ Wg, const float* __restrict__ bg,
    const float* __restrict__ Wh, const float* __restrict__ bh,
    unsigned short* __restrict__ fb, unsigned short* __restrict__ gb,
    unsigned short* __restrict__ htb)
{
    const float* W; const float* bias;
    if (blockIdx.z == 0)      { W = Wf; bias = bf; }
    else if (blockIdx.z == 1) { W = Wg; bias = bg; }
    else                      { W = Wh; bias = bh; }

    __shared__ __align__(16) float ast[32 * 32];    // [c][r]
    __shared__ __align__(16) float bs [32 * 128];   // [c][d]

    const int tid = threadIdx.x;
    const int tx = tid & 31, ty = tid >> 5;
    const int r0 = blockIdx.x * 32;

    float acc[4][4] = {};

    for (int cc = 0; cc < 128; cc += 32) {
        __syncthreads();
        {   // stage A (transpose): 1024 floats
            int r = tid >> 3, c4 = tid & 7;
            float4 v = *(const float4*)&x[(size_t)(r0 + r) * NC + cc + c4 * 4];
            ast[(c4 * 4 + 0) * 32 + r] = v.x;
            ast[(c4 * 4 + 1) * 32 + r] = v.y;
            ast[(c4 * 4 + 2) * 32 + r] = v.z;
            ast[(c4 * 4 + 3) * 32 + r] = v.w;
        }
        #pragma unroll
        for (int i = 0; i < 4; i++) {
            int idx = tid + i * 256;
            *(float4*)&bs[idx * 4] = *(const float4*)&W[(size_t)cc * 128 + idx * 4];
        }
        __syncthreads();
        #pragma unroll
        for (int c = 0; c < 32; c++) {
            float4 a  = *(const float4*)&ast[c * 32 + ty * 4];
            float4 b4 = *(const float4*)&bs [c * 128 + tx * 4];
            acc[0][0] += a.x * b4.x; acc[0][1] += a.x * b4.y; acc[0][2] += a.x * b4.z; acc[0][3] += a.x * b4.w;
            acc[1][0] += a.y * b4.x; acc[1][1] += a.y * b4.y; acc[1][2] += a.y * b4.z; acc[1][3] += a.y * b4.w;
            acc[2][0] += a.z * b4.x; acc[2][1] += a.z * b4.y; acc[2][2] += a.z * b4.z; acc[2][3] += a.z * b4.w;
            acc[3][0] += a.w * b4.x; acc[3][1] += a.w * b4.y; acc[3][2] += a.w * b4.z; acc[3][3] += a.w * b4.w;
        }
    }

    float4 bb = *(const float4*)&bias[tx * 4];
    float bbv[4] = { bb.x, bb.y, bb.z, bb.w };

    if (blockIdx.z < 2) {
        // rows rr = r0+ty*4+i (tile T = r0>>5), cols cc = tx*4+j
        unsigned short* out = (blockIdx.z == 0) ? fb : gb;
        const int kc = tx >> 2, hi2 = (tx >> 1) & 1, j0 = (tx & 1) * 4;
        const size_t base = ((size_t)(r0 >> 5) * 8 + kc) * 512;
        #pragma unroll
        for (int i = 0; i < 4; i++) {
            ushort4 v;
            v.x = f2bf(acc[i][0] + bbv[0]);
            v.y = f2bf(acc[i][1] + bbv[1]);
            v.z = f2bf(acc[i][2] + bbv[2]);
            v.w = f2bf(acc[i][3] + bbv[3]);
            int lane = (ty * 4 + i) + 32 * hi2;
            *(ushort4*)&out[base + (size_t)lane * 8 + j0] = v;
        }
    } else {
        // h: element (c = tx*4+j, n = (r0&4095)+ty*4+i), b = r0>>12
        const int b   = r0 >> 12;
        const int ncc = (r0 & (NN - 1)) >> 5;     // n-chunk
        const int s   = ty >> 2, hj = (ty >> 1) & 1, jj0 = (ty & 1) * 4;
        const int cb  = tx >> 3;
        #pragma unroll
        for (int j = 0; j < 4; j++) {
            int c = tx * 4 + j;
            int lane = (c & 31) + 32 * hj;
            ushort4 v;
            v.x = f2bf(acc[0][j] + bbv[j]);
            v.y = f2bf(acc[1][j] + bbv[j]);
            v.z = f2bf(acc[2][j] + bbv[j]);
            v.w = f2bf(acc[3][j] + bbv[j]);
            size_t off = ((((size_t)(b * 4 + cb) * 128 + ncc) * 2 + s) * 64 + lane) * 8 + jj0;
            *(ushort4*)&htb[off] = v;
        }
    }
}

// ---------------------------------------------------------------------------
// K2: softmax normalizer C[n] = -(SBIAS + log2(sum_m exp(S-30))) via 32x32 MFMA.
// XCD-aware work swizzle: wk = (lin%8)*64 + lin/8 so XCD k owns batch k
// entirely (gx[b=k] = 1MB -> L2 resident). x2 m-tile unroll; setprio around
// the MFMA cluster. Bit-identical C[n].
// ---------------------------------------------------------------------------
__global__ __launch_bounds__(512, 2) void k_stats(
    const unsigned short* __restrict__ fb, const unsigned short* __restrict__ gb,
    float* __restrict__ Cout)
{
    const int lin = (int)(blockIdx.x + (NN / 64) * blockIdx.y);   // 0..511
    const int wk  = (lin & 7) * 64 + (lin >> 3);
    const int b   = wk >> 6;
    const int xt  = wk & 63;

    const int tid = threadIdx.x;
    const int w = tid >> 6;
    const int l = tid & 63;
    const int t = w & 1, q = w >> 1;
    const int nbase = xt * 64 + t * 32;

    // hoist B-frags: fx tile tn = b*128 + nbase/32
    const size_t fbase = ((size_t)(b * 128 + (nbase >> 5)) * 8) * 512 + (size_t)l * 8;
    bf16x8 bfr[8];
    #pragma unroll
    for (int kc = 0; kc < 8; kc++)
        bfr[kc] = *(const bf16x8*)&fb[fbase + kc * 512];

    float sum = 0.f;
    for (int mt = 0; mt < 32; mt += 2) {
        const size_t gbaseA = ((size_t)(b * 128 + q * 32 + mt) * 8) * 512 + (size_t)l * 8;
        const size_t gbaseB = gbaseA + 8 * 512;
        f32x16 S0A = {}; f32x16 S1A = {};
        f32x16 S0B = {}; f32x16 S1B = {};
        __builtin_amdgcn_s_setprio(1);
        #pragma unroll
        for (int kc = 0; kc < 8; kc += 2) {
            S0A = __builtin_amdgcn_mfma_f32_32x32x16_bf16(*(const bf16x8*)&gb[gbaseA + kc * 512], bfr[kc], S0A, 0, 0, 0);
            S1A = __builtin_amdgcn_mfma_f32_32x32x16_bf16(*(const bf16x8*)&gb[gbaseA + (kc + 1) * 512], bfr[kc + 1], S1A, 0, 0, 0);
            S0B = __builtin_amdgcn_mfma_f32_32x32x16_bf16(*(const bf16x8*)&gb[gbaseB + kc * 512], bfr[kc], S0B, 0, 0, 0);
            S1B = __builtin_amdgcn_mfma_f32_32x32x16_bf16(*(const bf16x8*)&gb[gbaseB + (kc + 1) * 512], bfr[kc + 1], S1B, 0, 0, 0);
        }
        __builtin_amdgcn_s_setprio(0);
        #pragma unroll
        for (int r = 0; r < 16; r++)
            sum += fexp2(__builtin_fmaf(S0A[r] + S1A[r], L2E, -SBIAS));
        #pragma unroll
        for (int r = 0; r < 16; r++)
            sum += fexp2(__builtin_fmaf(S0B[r] + S1B[r], L2E, -SBIAS));
    }

    // lanes l and l^32 hold the same n (col), different m rows: combine
    sum += __shfl_xor(sum, 32, 64);

    // combine the 4 m-quarters per n-tile
    __shared__ float red[8][32];
    if (l < 32) red[w][l] = sum;
    __syncthreads();
    if (q == 0 && l < 32) {
        float tot = red[t][l] + red[t + 2][l] + red[t + 4][l] + red[t + 6][l];
        Cout[(size_t)b * NN + nbase + l] = -(SBIAS + flog2(tot));
    }
}

// ---------------------------------------------------------------------------
// K3: O[b][c][m] = sum_n ht[b][c][n] * alpha[n][m]; alpha = exp2(S*L2E + C[n]).
// LDS byte-copy staging (double-buffered, 1 barrier/chunk), hoisted gx
// B-frags, permlane32_swap in-register transpose, XCD-aware work swizzle.
// ---------------------------------------------------------------------------
__global__ __launch_bounds__(512, 2) void k_out(
    const unsigned short* __restrict__ fb, const unsigned short* __restrict__ gb,
    const unsigned short* __restrict__ htb, const float* __restrict__ Cn,
    float* __restrict__ O0, float* __restrict__ O1, float* __restrict__ O2,
    float* __restrict__ Od, int nsplit)
{
    const int total = 16 * nsplit * NB;
    const int lin = (int)(blockIdx.x + 16 * (blockIdx.y + nsplit * blockIdx.z));
    const int wk  = (lin & 7) * (total >> 3) + (lin >> 3);
    const int mblk = wk & 15;
    const int rest = wk >> 4;
    const int y = rest % nsplit;
    const int b = rest / nsplit;

    const int tid = threadIdx.x;
    const int w = tid >> 6, l = tid & 63;
    const int lr = l & 31, hi = l >> 5;
    const int m0 = mblk * 256 + w * 32;

    __shared__ __align__(16) char ldsF[2][8192];
    __shared__ __align__(16) char ldsH[2][8192];

    const int chunks = (NN / 32) / nsplit;
    const int c0g = y * chunks;                // first global n-chunk
    float* O = Od;
    if (y + 1 < nsplit)
        O = (y == 0) ? O0 : ((y == 1) ? O1 : O2);

    // hoist gx B-frags: tile b*128 + m0/32 = b*128 + mblk*8 + w
    const size_t gbase = ((size_t)(b * 128 + mblk * 8 + w) * 8) * 512 + (size_t)l * 8;
    bf16x8 gfr[8];
    #pragma unroll
    for (int kc = 0; kc < 8; kc++)
        gfr[kc] = *(const bf16x8*)&gb[gbase + kc * 512];

    const float* Cb = Cn + (size_t)b * NN;

    // ---- staging geometry (byte-exact copy of packed tiles) ----
    const size_t fstage0 = (size_t)b * 128 * 4096 + (size_t)tid * 8;   // + ncg*4096
    const int p = tid >> 6, pcb = p >> 1, ps = p & 1;
    const size_t hstage0 = ((size_t)(b * 4 + pcb) * 256 + ps) * 512 + (size_t)(tid & 63) * 8;  // + ncg*1024

    f32x16 acc[4] = { {}, {}, {}, {} };

    // preload first chunk into regs
    uint4 fv = *(const uint4*)&fb[fstage0 + (size_t)c0g * 4096];
    uint4 hv = *(const uint4*)&htb[hstage0 + (size_t)c0g * 1024];

    for (int nc = 0; nc < chunks; nc++) {
        const int cur = nc & 1;
        const int ncg = c0g + nc;              // global n-chunk index
        const int n0 = ncg * 32;
        const int ncgN = c0g + ((nc + 1 < chunks) ? nc + 1 : nc);

        // ---- stage this chunk (byte-identical copy), one barrier
        *(uint4*)(ldsF[cur] + tid * 16) = fv;
        *(uint4*)(ldsH[cur] + tid * 16) = hv;
        __syncthreads();

        // ---- issue next chunk's loads (consumed at next iteration's ds_write)
        fv = *(const uint4*)&fb[fstage0 + (size_t)ncgN * 4096];
        hv = *(const uint4*)&htb[hstage0 + (size_t)ncgN * 1024];

        // ---- fx A-frags from LDS (same bytes as r9 global reads)
        bf16x8 fcur[8];
        #pragma unroll
        for (int kc = 0; kc < 8; kc++)
            fcur[kc] = *(const bf16x8*)(ldsF[cur] + kc * 1024 + l * 16);

        // ---- ht A-frags from LDS
        bf16x8 hA[8];
        #pragma unroll
        for (int cb = 0; cb < 4; cb++) {
            hA[2 * cb]     = *(const bf16x8*)(ldsH[cur] + (cb * 2 + 0) * 1024 + l * 16);
            hA[2 * cb + 1] = *(const bf16x8*)(ldsH[cur] + (cb * 2 + 1) * 1024 + l * 16);
        }
        // ---- Cn loads
        float4 Cv[4];
        #pragma unroll
        for (int q = 0; q < 4; q++)
            Cv[q] = *(const float4*)&Cb[n0 + q * 8 + hi * 4];

        // ---- S tile 32n x 32m, K=128
        f32x16 S0 = {}; f32x16 S1 = {};
        #pragma unroll
        for (int kc = 0; kc < 8; kc += 2) {
            S0 = __builtin_amdgcn_mfma_f32_32x32x16_bf16(fcur[kc], gfr[kc], S0, 0, 0, 0);
            S1 = __builtin_amdgcn_mfma_f32_32x32x16_bf16(fcur[kc + 1], gfr[kc + 1], S1, 0, 0, 0);
        }

        // ---- alpha = exp2(S*L2E + C[n]); reg r -> n-off = (r&3)+8*(r>>2)+4*hi
        unsigned pk[8];
        #pragma unroll
        for (int pp = 0; pp < 8; pp++) {
            int r0i = 2 * pp, r1i = 2 * pp + 1;
            float a0 = fexp2(__builtin_fmaf(S0[r0i] + S1[r0i], L2E, Cv[r0i >> 2][r0i & 3]));
            float a1 = fexp2(__builtin_fmaf(S0[r1i] + S1[r1i], L2E, Cv[r1i >> 2][r1i & 3]));
            asm("v_cvt_pk_bf16_f32 %0, %1, %2" : "=v"(pk[pp]) : "v"(a0), "v"(a1));
        }

        // ---- assemble PV B-frags via half-wave swaps (bit-identical to the
        //      old shfl_xor+select): after swap, pk[0..3] = old b0 words,
        //      pk[4..7] = old b1 words.
        asm("v_permlane32_swap_b32 %0, %1" : "+v"(pk[0]), "+v"(pk[2]));
        asm("v_permlane32_swap_b32 %0, %1" : "+v"(pk[1]), "+v"(pk[3]));
        asm("v_permlane32_swap_b32 %0, %1" : "+v"(pk[4]), "+v"(pk[6]));
        asm("v_permlane32_swap_b32 %0, %1" : "+v"(pk[5]), "+v"(pk[7]));
        uint4 b0, b1;
        b0.x = pk[0]; b0.y = pk[1]; b0.z = pk[2]; b0.w = pk[3];
        b1.x = pk[4]; b1.y = pk[5]; b1.z = pk[6]; b1.w = pk[7];
        bf16x8 B0 = __builtin_bit_cast(bf16x8, b0);
        bf16x8 B1 = __builtin_bit_cast(bf16x8, b1);

        // ---- PV: acc[cb] += ht[cb*32+row][n-chunk] * alpha^T
        #pragma unroll
        for (int cb = 0; cb < 4; cb++) {
            acc[cb] = __builtin_amdgcn_mfma_f32_32x32x16_bf16(hA[2 * cb],     B0, acc[cb], 0, 0, 0);
            acc[cb] = __builtin_amdgcn_mfma_f32_32x32x16_bf16(hA[2 * cb + 1], B1, acc[cb], 0, 0, 0);
        }
        // no trailing barrier: next iter writes the OTHER buffer; the barrier
        // of iteration nc separates iter nc-1's reads from iter nc+1's writes.
    }

    // ---- store: O[c = cb*32 + (reg&3)+8*(reg>>2)+4*hi][m = m0+lr]
    #pragma unroll
    for (int cb = 0; cb < 4; cb++) {
        #pragma unroll
        for (int r = 0; r < 16; r++) {
            int row = (r & 3) + 8 * (r >> 2) + 4 * hi;
            O[((size_t)b * NC + cb * 32 + row) * NN + m0 + lr] = acc[cb][r];
        }
    }
}

// ---------------------------------------------------------------------------
// K4: final projection, IN PLACE on d_out viewed as [32768][128] fp32,
// summing up to 3 extra partial-O buffers.
// ---------------------------------------------------------------------------
__global__ __launch_bounds__(256) void k_vproj(
    float* __restrict__ o, const float* __restrict__ E0,
    const float* __restrict__ E1, const float* __restrict__ E2,
    const float* __restrict__ Wv, const float* __restrict__ bv, int nextra)
{
    __shared__ __align__(16) float ast[32 * 32];
    __shared__ __align__(16) float bs [32 * 128];

    const int tid = threadIdx.x;
    const int tx = tid & 31, ty = tid >> 5;
    const int r0 = blockIdx.x * 32;

    float acc[4][4] = {};

    for (int cc = 0; cc < 128; cc += 32) {
        __syncthreads();
        {
            int r = tid >> 3, c4 = tid & 7;
            size_t idx = (size_t)(r0 + r) * NC + cc + c4 * 4;
            float4 v = *(const float4*)&o[idx];
            if (nextra > 0) {
                float4 u = *(const float4*)&E0[idx];
                v.x += u.x; v.y += u.y; v.z += u.z; v.w += u.w;
            }
            if (nextra > 1) {
                float4 u = *(const float4*)&E1[idx];
                v.x += u.x; v.y += u.y; v.z += u.z; v.w += u.w;
            }
            if (nextra > 2) {
                float4 u = *(const float4*)&E2[idx];
                v.x += u.x; v.y += u.y; v.z += u.z; v.w += u.w;
            }
            ast[(c4 * 4 + 0) * 32 + r] = v.x;
            ast[(c4 * 4 + 1) * 32 + r] = v.y;
            ast[(c4 * 4 + 2) * 32 + r] = v.z;
            ast[(c4 * 4 + 3) * 32 + r] = v.w;
        }
        #pragma unroll
        for (int i = 0; i < 4; i++) {
            int idx = tid + i * 256;
            *(float4*)&bs[idx * 4] = *(const float4*)&Wv[(size_t)cc * 128 + idx * 4];
        }
        __syncthreads();
        #pragma unroll
        for (int c = 0; c < 32; c++) {
            float4 a  = *(const float4*)&ast[c * 32 + ty * 4];
            float4 b4 = *(const float4*)&bs [c * 128 + tx * 4];
            acc[0][0] += a.x * b4.x; acc[0][1] += a.x * b4.y; acc[0][2] += a.x * b4.z; acc[0][3] += a.x * b4.w;
            acc[1][0] += a.y * b4.x; acc[1][1] += a.y * b4.y; acc[1][2] += a.y * b4.z; acc[1][3] += a.y * b4.w;
            acc[2][0] += a.z * b4.x; acc[2][1] += a.z * b4.y; acc[2][2] += a.z * b4.z; acc[2][3] += a.z * b4.w;
            acc[3][0] += a.w * b4.x; acc[3][1] += a.w * b4.y; acc[3][2] += a.w * b4.z; acc[3][3] += a.w * b4.w;
        }
    }
    float4 bb = *(const float4*)&bv[tx * 4];
    #pragma unroll
    for (int i = 0; i < 4; i++) {
        float4 r;
        r.x = acc[i][0] + bb.x; r.y = acc[i][1] + bb.y;
        r.z = acc[i][2] + bb.z; r.w = acc[i][3] + bb.w;
        *(float4*)&o[(size_t)(r0 + ty * 4 + i) * NC + tx * 4] = r;
    }
}

// ---------------------------------------------------------------------------
extern "C" void kernel_launch(void* const* d_in, const int* in_sizes, int n_in,
                              void* d_out, int out_size, void* d_ws, size_t ws_size,
                              hipStream_t stream)
{
    const float* x  = (const float*)d_in[0];
    const float* Wf = (const float*)d_in[1];
    const float* bf = (const float*)d_in[2];
    const float* Wg = (const float*)d_in[3];
    const float* bg = (const float*)d_in[4];
    const float* Wh = (const float*)d_in[5];
    const float* bh = (const float*)d_in[6];
    const float* Wv = (const float*)d_in[7];
    const float* bv = (const float*)d_in[8];
    float* out = (float*)d_out;

    // ws: fb, gb (packed bf16), htb (packed bf16), Cn (f32 [B*N]), O partials
    unsigned short* fbp = (unsigned short*)d_ws;
    unsigned short* gbp = fbp + (size_t)NB * NN * NC;
    unsigned short* htp = gbp + (size_t)NB * NN * NC;
    float* Cn = (float*)(htp + (size_t)NB * NN * NC);
    float* Opart = Cn + (size_t)NB * NN;
    const size_t osz = (size_t)NB * NC * NN;           // elements per O buffer
    size_t base = (size_t)((char*)Opart - (char*)d_ws);
    // nsplit=2: 256 k_out blocks (exactly 1/CU, single round) and k_vproj
    // reads only one extra partial buffer.
    int nsplit = (ws_size >= base + osz * 4) ? 2 : 1;
    float* O0 = Opart;
    float* O1 = Opart + osz;
    float* O2 = Opart + 2 * osz;

    // 1) projections -> packed bf16
    k_proj<<<dim3(1024, 1, 3), 256, 0, stream>>>(x, Wf, bf, Wg, bg, Wh, bh, fbp, gbp, htp);

    // 2) softmax normalizers C[n]
    k_stats<<<dim3(NN / 64, NB), 512, 0, stream>>>(fbp, gbp, Cn);

    // 3) attention output, O staged [B,C,N]: last n-split into d_out, rest into ws
    k_out<<<dim3(NN / 256, nsplit, NB), 512, 0, stream>>>(fbp, gbp, htp, Cn, O0, O1, O2, out, nsplit);

    // 4) final projection in place (implements the [B,C,N]->[B,N,C] flat reshape)
    k_vproj<<<dim3(1024), 256, 0, stream>>>(out, O0, O1, O2, Wv, bv, nsplit - 1);
}

// Round 20
// 208.789 us; speedup vs baseline: 1.0099x; 1.0099x over previous
//
#include <hip/hip_runtime.h>
#include <math.h>

#define NB 8
#define NN 4096   // pixels per batch
#define NC 128    // channels

typedef __attribute__((ext_vector_type(8)))  short bf16x8;
typedef __attribute__((ext_vector_type(4)))  float f32x4;
typedef __attribute__((ext_vector_type(16))) float f32x16;

#define L2E   1.4426950408889634f
#define SBIAS 43.2808512266689f   /* 30 * log2(e) */

static __device__ __forceinline__ float fexp2(float x) { return __builtin_amdgcn_exp2f(x); }
static __device__ __forceinline__ float flog2(float x) { return __builtin_amdgcn_logf(x); }

static __device__ __forceinline__ unsigned short f2bf(float f) {
    unsigned u = __builtin_bit_cast(unsigned, f);
    return (unsigned short)((u + 0x7FFFu + ((u >> 16) & 1u)) >> 16);
}

// ---------------------------------------------------------------------------
// PACKED LAYOUTS (bf16 element offsets):
//  fx/gx: tile T = (b*128 + n>>5), kc = k>>4:
//    fpk[((T*8 + kc)*64 + lane)*8 + j] = x[b][n = 32*(T&127) + (lane&31)]
//                                         [k = kc*16 + (lane>>5)*8 + j]
//  ht: hpk[((((b*4+cb)*128 + nc)*2 + s)*64 + lane)*8 + j]
//       = h[b][c = cb*32 + (lane&31)][n = nc*32 + s*16 + (lane>>5)*8 + j]
// Fragment loads become base + lane*16 : perfectly coalesced.
// ---------------------------------------------------------------------------

// ---------------------------------------------------------------------------
// K1: FUSED projections f,g,h (fp32 compute, bf16 PACKED outputs).
// One block = 32 x-rows -> all three outputs: x tile staged ONCE, the three
// 32x128 W chunks staged per cc iteration (LDS 4KB + 48KB). Per-output FMA
// order identical to the unfused version -> bit-identical packed outputs.
// Grid: 1024 blocks.
// ---------------------------------------------------------------------------
__global__ __launch_bounds__(256) void k_proj(
    const float* __restrict__ x,
    const float* __restrict__ Wf, const float* __restrict__ bf,
    const float* __restrict__ Wg, const float* __restrict__ bg,
    const float* __restrict__ Wh, const float* __restrict__ bh,
    unsigned short* __restrict__ fb, unsigned short* __restrict__ gb,
    unsigned short* __restrict__ htb)
{
    __shared__ __align__(16) float ast[32 * 32];       // [c][r]
    __shared__ __align__(16) float bs [3][32 * 128];   // [z][c][d]

    const int tid = threadIdx.x;
    const int tx = tid & 31, ty = tid >> 5;
    const int r0 = blockIdx.x * 32;

    float acc[3][4][4] = {};

    for (int cc = 0; cc < 128; cc += 32) {
        __syncthreads();
        {   // stage A (transpose): 1024 floats, once for all three outputs
            int r = tid >> 3, c4 = tid & 7;
            float4 v = *(const float4*)&x[(size_t)(r0 + r) * NC + cc + c4 * 4];
            ast[(c4 * 4 + 0) * 32 + r] = v.x;
            ast[(c4 * 4 + 1) * 32 + r] = v.y;
            ast[(c4 * 4 + 2) * 32 + r] = v.z;
            ast[(c4 * 4 + 3) * 32 + r] = v.w;
        }
        #pragma unroll
        for (int i = 0; i < 4; i++) {
            int idx = tid + i * 256;
            *(float4*)&bs[0][idx * 4] = *(const float4*)&Wf[(size_t)cc * 128 + idx * 4];
            *(float4*)&bs[1][idx * 4] = *(const float4*)&Wg[(size_t)cc * 128 + idx * 4];
            *(float4*)&bs[2][idx * 4] = *(const float4*)&Wh[(size_t)cc * 128 + idx * 4];
        }
        __syncthreads();
        #pragma unroll
        for (int c = 0; c < 32; c++) {
            float4 a = *(const float4*)&ast[c * 32 + ty * 4];
            #pragma unroll
            for (int z = 0; z < 3; z++) {
                float4 b4 = *(const float4*)&bs[z][c * 128 + tx * 4];
                acc[z][0][0] += a.x * b4.x; acc[z][0][1] += a.x * b4.y; acc[z][0][2] += a.x * b4.z; acc[z][0][3] += a.x * b4.w;
                acc[z][1][0] += a.y * b4.x; acc[z][1][1] += a.y * b4.y; acc[z][1][2] += a.y * b4.z; acc[z][1][3] += a.y * b4.w;
                acc[z][2][0] += a.z * b4.x; acc[z][2][1] += a.z * b4.y; acc[z][2][2] += a.z * b4.z; acc[z][2][3] += a.z * b4.w;
                acc[z][3][0] += a.w * b4.x; acc[z][3][1] += a.w * b4.y; acc[z][3][2] += a.w * b4.z; acc[z][3][3] += a.w * b4.w;
            }
        }
    }

    float4 bbf = *(const float4*)&bf[tx * 4];
    float4 bbg = *(const float4*)&bg[tx * 4];
    float4 bbh = *(const float4*)&bh[tx * 4];
    float bfv[4] = { bbf.x, bbf.y, bbf.z, bbf.w };
    float bgv[4] = { bbg.x, bbg.y, bbg.z, bbg.w };
    float bhv[4] = { bbh.x, bbh.y, bbh.z, bbh.w };

    // ---- f, g: packed fx/gx writes (same addressing as unfused version)
    {
        const int kc = tx >> 2, hi2 = (tx >> 1) & 1, j0 = (tx & 1) * 4;
        const size_t base = ((size_t)(r0 >> 5) * 8 + kc) * 512;
        #pragma unroll
        for (int i = 0; i < 4; i++) {
            int lane = (ty * 4 + i) + 32 * hi2;
            ushort4 vf, vg;
            vf.x = f2bf(acc[0][i][0] + bfv[0]);
            vf.y = f2bf(acc[0][i][1] + bfv[1]);
            vf.z = f2bf(acc[0][i][2] + bfv[2]);
            vf.w = f2bf(acc[0][i][3] + bfv[3]);
            *(ushort4*)&fb[base + (size_t)lane * 8 + j0] = vf;
            vg.x = f2bf(acc[1][i][0] + bgv[0]);
            vg.y = f2bf(acc[1][i][1] + bgv[1]);
            vg.z = f2bf(acc[1][i][2] + bgv[2]);
            vg.w = f2bf(acc[1][i][3] + bgv[3]);
            *(ushort4*)&gb[base + (size_t)lane * 8 + j0] = vg;
        }
    }
    // ---- h: packed ht write (same addressing as unfused version)
    {
        const int b   = r0 >> 12;
        const int ncc = (r0 & (NN - 1)) >> 5;     // n-chunk
        const int s   = ty >> 2, hj = (ty >> 1) & 1, jj0 = (ty & 1) * 4;
        const int cb  = tx >> 3;
        #pragma unroll
        for (int j = 0; j < 4; j++) {
            int c = tx * 4 + j;
            int lane = (c & 31) + 32 * hj;
            ushort4 v;
            v.x = f2bf(acc[2][0][j] + bhv[j]);
            v.y = f2bf(acc[2][1][j] + bhv[j]);
            v.z = f2bf(acc[2][2][j] + bhv[j]);
            v.w = f2bf(acc[2][3][j] + bhv[j]);
            size_t off = ((((size_t)(b * 4 + cb) * 128 + ncc) * 2 + s) * 64 + lane) * 8 + jj0;
            *(ushort4*)&htb[off] = v;
        }
    }
}

// ---------------------------------------------------------------------------
// K2: softmax normalizer C[n] = -(SBIAS + log2(sum_m exp(S-30))) via 32x32 MFMA.
// (verbatim r19: XCD swizzle, x2 unroll, setprio)
// ---------------------------------------------------------------------------
__global__ __launch_bounds__(512, 2) void k_stats(
    const unsigned short* __restrict__ fb, const unsigned short* __restrict__ gb,
    float* __restrict__ Cout)
{
    const int lin = (int)(blockIdx.x + (NN / 64) * blockIdx.y);   // 0..511
    const int wk  = (lin & 7) * 64 + (lin >> 3);
    const int b   = wk >> 6;
    const int xt  = wk & 63;

    const int tid = threadIdx.x;
    const int w = tid >> 6;
    const int l = tid & 63;
    const int t = w & 1, q = w >> 1;
    const int nbase = xt * 64 + t * 32;

    // hoist B-frags: fx tile tn = b*128 + nbase/32
    const size_t fbase = ((size_t)(b * 128 + (nbase >> 5)) * 8) * 512 + (size_t)l * 8;
    bf16x8 bfr[8];
    #pragma unroll
    for (int kc = 0; kc < 8; kc++)
        bfr[kc] = *(const bf16x8*)&fb[fbase + kc * 512];

    float sum = 0.f;
    for (int mt = 0; mt < 32; mt += 2) {
        const size_t gbaseA = ((size_t)(b * 128 + q * 32 + mt) * 8) * 512 + (size_t)l * 8;
        const size_t gbaseB = gbaseA + 8 * 512;
        f32x16 S0A = {}; f32x16 S1A = {};
        f32x16 S0B = {}; f32x16 S1B = {};
        __builtin_amdgcn_s_setprio(1);
        #pragma unroll
        for (int kc = 0; kc < 8; kc += 2) {
            S0A = __builtin_amdgcn_mfma_f32_32x32x16_bf16(*(const bf16x8*)&gb[gbaseA + kc * 512], bfr[kc], S0A, 0, 0, 0);
            S1A = __builtin_amdgcn_mfma_f32_32x32x16_bf16(*(const bf16x8*)&gb[gbaseA + (kc + 1) * 512], bfr[kc + 1], S1A, 0, 0, 0);
            S0B = __builtin_amdgcn_mfma_f32_32x32x16_bf16(*(const bf16x8*)&gb[gbaseB + kc * 512], bfr[kc], S0B, 0, 0, 0);
            S1B = __builtin_amdgcn_mfma_f32_32x32x16_bf16(*(const bf16x8*)&gb[gbaseB + (kc + 1) * 512], bfr[kc + 1], S1B, 0, 0, 0);
        }
        __builtin_amdgcn_s_setprio(0);
        #pragma unroll
        for (int r = 0; r < 16; r++)
            sum += fexp2(__builtin_fmaf(S0A[r] + S1A[r], L2E, -SBIAS));
        #pragma unroll
        for (int r = 0; r < 16; r++)
            sum += fexp2(__builtin_fmaf(S0B[r] + S1B[r], L2E, -SBIAS));
    }

    // lanes l and l^32 hold the same n (col), different m rows: combine
    sum += __shfl_xor(sum, 32, 64);

    // combine the 4 m-quarters per n-tile
    __shared__ float red[8][32];
    if (l < 32) red[w][l] = sum;
    __syncthreads();
    if (q == 0 && l < 32) {
        float tot = red[t][l] + red[t + 2][l] + red[t + 4][l] + red[t + 6][l];
        Cout[(size_t)b * NN + nbase + l] = -(SBIAS + flog2(tot));
    }
}

// ---------------------------------------------------------------------------
// K3: O[b][c][m] = sum_n ht[b][c][n] * alpha[n][m]; alpha = exp2(S*L2E + C[n]).
// (verbatim r19: LDS byte-copy staging, hoisted gx, permlane transpose,
//  XCD-aware work swizzle)
// ---------------------------------------------------------------------------
__global__ __launch_bounds__(512, 2) void k_out(
    const unsigned short* __restrict__ fb, const unsigned short* __restrict__ gb,
    const unsigned short* __restrict__ htb, const float* __restrict__ Cn,
    float* __restrict__ O0, float* __restrict__ O1, float* __restrict__ O2,
    float* __restrict__ Od, int nsplit)
{
    const int total = 16 * nsplit * NB;
    const int lin = (int)(blockIdx.x + 16 * (blockIdx.y + nsplit * blockIdx.z));
    const int wk  = (lin & 7) * (total >> 3) + (lin >> 3);
    const int mblk = wk & 15;
    const int rest = wk >> 4;
    const int y = rest % nsplit;
    const int b = rest / nsplit;

    const int tid = threadIdx.x;
    const int w = tid >> 6, l = tid & 63;
    const int lr = l & 31, hi = l >> 5;
    const int m0 = mblk * 256 + w * 32;

    __shared__ __align__(16) char ldsF[2][8192];
    __shared__ __align__(16) char ldsH[2][8192];

    const int chunks = (NN / 32) / nsplit;
    const int c0g = y * chunks;                // first global n-chunk
    float* O = Od;
    if (y + 1 < nsplit)
        O = (y == 0) ? O0 : ((y == 1) ? O1 : O2);

    // hoist gx B-frags: tile b*128 + m0/32 = b*128 + mblk*8 + w
    const size_t gbase = ((size_t)(b * 128 + mblk * 8 + w) * 8) * 512 + (size_t)l * 8;
    bf16x8 gfr[8];
    #pragma unroll
    for (int kc = 0; kc < 8; kc++)
        gfr[kc] = *(const bf16x8*)&gb[gbase + kc * 512];

    const float* Cb = Cn + (size_t)b * NN;

    // ---- staging geometry (byte-exact copy of packed tiles) ----
    const size_t fstage0 = (size_t)b * 128 * 4096 + (size_t)tid * 8;   // + ncg*4096
    const int p = tid >> 6, pcb = p >> 1, ps = p & 1;
    const size_t hstage0 = ((size_t)(b * 4 + pcb) * 256 + ps) * 512 + (size_t)(tid & 63) * 8;  // + ncg*1024

    f32x16 acc[4] = { {}, {}, {}, {} };

    // preload first chunk into regs
    uint4 fv = *(const uint4*)&fb[fstage0 + (size_t)c0g * 4096];
    uint4 hv = *(const uint4*)&htb[hstage0 + (size_t)c0g * 1024];

    for (int nc = 0; nc < chunks; nc++) {
        const int cur = nc & 1;
        const int ncg = c0g + nc;              // global n-chunk index
        const int n0 = ncg * 32;
        const int ncgN = c0g + ((nc + 1 < chunks) ? nc + 1 : nc);

        // ---- stage this chunk (byte-identical copy), one barrier
        *(uint4*)(ldsF[cur] + tid * 16) = fv;
        *(uint4*)(ldsH[cur] + tid * 16) = hv;
        __syncthreads();

        // ---- issue next chunk's loads (consumed at next iteration's ds_write)
        fv = *(const uint4*)&fb[fstage0 + (size_t)ncgN * 4096];
        hv = *(const uint4*)&htb[hstage0 + (size_t)ncgN * 1024];

        // ---- fx A-frags from LDS (same bytes as r9 global reads)
        bf16x8 fcur[8];
        #pragma unroll
        for (int kc = 0; kc < 8; kc++)
            fcur[kc] = *(const bf16x8*)(ldsF[cur] + kc * 1024 + l * 16);

        // ---- ht A-frags from LDS
        bf16x8 hA[8];
        #pragma unroll
        for (int cb = 0; cb < 4; cb++) {
            hA[2 * cb]     = *(const bf16x8*)(ldsH[cur] + (cb * 2 + 0) * 1024 + l * 16);
            hA[2 * cb + 1] = *(const bf16x8*)(ldsH[cur] + (cb * 2 + 1) * 1024 + l * 16);
        }
        // ---- Cn loads
        float4 Cv[4];
        #pragma unroll
        for (int q = 0; q < 4; q++)
            Cv[q] = *(const float4*)&Cb[n0 + q * 8 + hi * 4];

        // ---- S tile 32n x 32m, K=128
        f32x16 S0 = {}; f32x16 S1 = {};
        #pragma unroll
        for (int kc = 0; kc < 8; kc += 2) {
            S0 = __builtin_amdgcn_mfma_f32_32x32x16_bf16(fcur[kc], gfr[kc], S0, 0, 0, 0);
            S1 = __builtin_amdgcn_mfma_f32_32x32x16_bf16(fcur[kc + 1], gfr[kc + 1], S1, 0, 0, 0);
        }

        // ---- alpha = exp2(S*L2E + C[n]); reg r -> n-off = (r&3)+8*(r>>2)+4*hi
        unsigned pk[8];
        #pragma unroll
        for (int pp = 0; pp < 8; pp++) {
            int r0i = 2 * pp, r1i = 2 * pp + 1;
            float a0 = fexp2(__builtin_fmaf(S0[r0i] + S1[r0i], L2E, Cv[r0i >> 2][r0i & 3]));
            float a1 = fexp2(__builtin_fmaf(S0[r1i] + S1[r1i], L2E, Cv[r1i >> 2][r1i & 3]));
            asm("v_cvt_pk_bf16_f32 %0, %1, %2" : "=v"(pk[pp]) : "v"(a0), "v"(a1));
        }

        // ---- assemble PV B-frags via half-wave swaps (bit-identical to the
        //      old shfl_xor+select): after swap, pk[0..3] = old b0 words,
        //      pk[4..7] = old b1 words.
        asm("v_permlane32_swap_b32 %0, %1" : "+v"(pk[0]), "+v"(pk[2]));
        asm("v_permlane32_swap_b32 %0, %1" : "+v"(pk[1]), "+v"(pk[3]));
        asm("v_permlane32_swap_b32 %0, %1" : "+v"(pk[4]), "+v"(pk[6]));
        asm("v_permlane32_swap_b32 %0, %1" : "+v"(pk[5]), "+v"(pk[7]));
        uint4 b0, b1;
        b0.x = pk[0]; b0.y = pk[1]; b0.z = pk[2]; b0.w = pk[3];
        b1.x = pk[4]; b1.y = pk[5]; b1.z = pk[6]; b1.w = pk[7];
        bf16x8 B0 = __builtin_bit_cast(bf16x8, b0);
        bf16x8 B1 = __builtin_bit_cast(bf16x8, b1);

        // ---- PV: acc[cb] += ht[cb*32+row][n-chunk] * alpha^T
        #pragma unroll
        for (int cb = 0; cb < 4; cb++) {
            acc[cb] = __builtin_amdgcn_mfma_f32_32x32x16_bf16(hA[2 * cb],     B0, acc[cb], 0, 0, 0);
            acc[cb] = __builtin_amdgcn_mfma_f32_32x32x16_bf16(hA[2 * cb + 1], B1, acc[cb], 0, 0, 0);
        }
        // no trailing barrier: next iter writes the OTHER buffer; the barrier
        // of iteration nc separates iter nc-1's reads from iter nc+1's writes.
    }

    // ---- store: O[c = cb*32 + (reg&3)+8*(reg>>2)+4*hi][m = m0+lr]
    #pragma unroll
    for (int cb = 0; cb < 4; cb++) {
        #pragma unroll
        for (int r = 0; r < 16; r++) {
            int row = (r & 3) + 8 * (r >> 2) + 4 * hi;
            O[((size_t)b * NC + cb * 32 + row) * NN + m0 + lr] = acc[cb][r];
        }
    }
}

// ---------------------------------------------------------------------------
// K4: final projection, IN PLACE on d_out viewed as [32768][128] fp32,
// summing up to 3 extra partial-O buffers.  (verbatim r19)
// ---------------------------------------------------------------------------
__global__ __launch_bounds__(256) void k_vproj(
    float* __restrict__ o, const float* __restrict__ E0,
    const float* __restrict__ E1, const float* __restrict__ E2,
    const float* __restrict__ Wv, const float* __restrict__ bv, int nextra)
{
    __shared__ __align__(16) float ast[32 * 32];
    __shared__ __align__(16) float bs [32 * 128];

    const int tid = threadIdx.x;
    const int tx = tid & 31, ty = tid >> 5;
    const int r0 = blockIdx.x * 32;

    float acc[4][4] = {};

    for (int cc = 0; cc < 128; cc += 32) {
        __syncthreads();
        {
            int r = tid >> 3, c4 = tid & 7;
            size_t idx = (size_t)(r0 + r) * NC + cc + c4 * 4;
            float4 v = *(const float4*)&o[idx];
            if (nextra > 0) {
                float4 u = *(const float4*)&E0[idx];
                v.x += u.x; v.y += u.y; v.z += u.z; v.w += u.w;
            }
            if (nextra > 1) {
                float4 u = *(const float4*)&E1[idx];
                v.x += u.x; v.y += u.y; v.z += u.z; v.w += u.w;
            }
            if (nextra > 2) {
                float4 u = *(const float4*)&E2[idx];
                v.x += u.x; v.y += u.y; v.z += u.z; v.w += u.w;
            }
            ast[(c4 * 4 + 0) * 32 + r] = v.x;
            ast[(c4 * 4 + 1) * 32 + r] = v.y;
            ast[(c4 * 4 + 2) * 32 + r] = v.z;
            ast[(c4 * 4 + 3) * 32 + r] = v.w;
        }
        #pragma unroll
        for (int i = 0; i < 4; i++) {
            int idx = tid + i * 256;
            *(float4*)&bs[idx * 4] = *(const float4*)&Wv[(size_t)cc * 128 + idx * 4];
        }
        __syncthreads();
        #pragma unroll
        for (int c = 0; c < 32; c++) {
            float4 a  = *(const float4*)&ast[c * 32 + ty * 4];
            float4 b4 = *(const float4*)&bs [c * 128 + tx * 4];
            acc[0][0] += a.x * b4.x; acc[0][1] += a.x * b4.y; acc[0][2] += a.x * b4.z; acc[0][3] += a.x * b4.w;
            acc[1][0] += a.y * b4.x; acc[1][1] += a.y * b4.y; acc[1][2] += a.y * b4.z; acc[1][3] += a.y * b4.w;
            acc[2][0] += a.z * b4.x; acc[2][1] += a.z * b4.y; acc[2][2] += a.z * b4.z; acc[2][3] += a.z * b4.w;
            acc[3][0] += a.w * b4.x; acc[3][1] += a.w * b4.y; acc[3][2] += a.w * b4.z; acc[3][3] += a.w * b4.w;
        }
    }
    float4 bb = *(const float4*)&bv[tx * 4];
    #pragma unroll
    for (int i = 0; i < 4; i++) {
        float4 r;
        r.x = acc[i][0] + bb.x; r.y = acc[i][1] + bb.y;
        r.z = acc[i][2] + bb.z; r.w = acc[i][3] + bb.w;
        *(float4*)&o[(size_t)(r0 + ty * 4 + i) * NC + tx * 4] = r;
    }
}

// ---------------------------------------------------------------------------
extern "C" void kernel_launch(void* const* d_in, const int* in_sizes, int n_in,
                              void* d_out, int out_size, void* d_ws, size_t ws_size,
                              hipStream_t stream)
{
    const float* x  = (const float*)d_in[0];
    const float* Wf = (const float*)d_in[1];
    const float* bf = (const float*)d_in[2];
    const float* Wg = (const float*)d_in[3];
    const float* bg = (const float*)d_in[4];
    const float* Wh = (const float*)d_in[5];
    const float* bh = (const float*)d_in[6];
    const float* Wv = (const float*)d_in[7];
    const float* bv = (const float*)d_in[8];
    float* out = (float*)d_out;

    // ws: fb, gb (packed bf16), htb (packed bf16), Cn (f32 [B*N]), O partials
    unsigned short* fbp = (unsigned short*)d_ws;
    unsigned short* gbp = fbp + (size_t)NB * NN * NC;
    unsigned short* htp = gbp + (size_t)NB * NN * NC;
    float* Cn = (float*)(htp + (size_t)NB * NN * NC);
    float* Opart = Cn + (size_t)NB * NN;
    const size_t osz = (size_t)NB * NC * NN;           // elements per O buffer
    size_t base = (size_t)((char*)Opart - (char*)d_ws);
    // nsplit=2: 256 k_out blocks (exactly 1/CU, single round) and k_vproj
    // reads only one extra partial buffer.
    int nsplit = (ws_size >= base + osz * 4) ? 2 : 1;
    float* O0 = Opart;
    float* O1 = Opart + osz;
    float* O2 = Opart + 2 * osz;

    // 1) fused projections -> packed bf16 (x read once)
    k_proj<<<dim3(1024), 256, 0, stream>>>(x, Wf, bf, Wg, bg, Wh, bh, fbp, gbp, htp);

    // 2) softmax normalizers C[n]
    k_stats<<<dim3(NN / 64, NB), 512, 0, stream>>>(fbp, gbp, Cn);

    // 3) attention output, O staged [B,C,N]: last n-split into d_out, rest into ws
    k_out<<<dim3(NN / 256, nsplit, NB), 512, 0, stream>>>(fbp, gbp, htp, Cn, O0, O1, O2, out, nsplit);

    // 4) final projection in place (implements the [B,C,N]->[B,N,C] flat reshape)
    k_vproj<<<dim3(1024), 256, 0, stream>>>(out, O0, O1, O2, Wv, bv, nsplit - 1);
}